// Round 23
// baseline (298.817 us; speedup 1.0000x reference)
//
#include <hip/hip_runtime.h>
#include <hip/hip_bf16.h>
#include <hip/hip_fp16.h>
#include <math.h>

#define N_NODES 50000
#define N_EDGES 600000
#define D_IN    44

// ---------------- bf16 helpers (bit ops, RNE pack) ----------------

__device__ __forceinline__ unsigned pack_bf2(float a, float b) {
    unsigned ua = __float_as_uint(a);
    ua = (ua + 0x7fffu + ((ua >> 16) & 1u)) >> 16;
    unsigned ub = __float_as_uint(b);
    ub = (ub + 0x7fffu + ((ub >> 16) & 1u)) & 0xffff0000u;
    return ua | ub;
}

// ---------------- CSR build ----------------

__global__ void k_zero(int* p, int n) {
    int i = blockIdx.x * blockDim.x + threadIdx.x;
    if (i < n) p[i] = 0;
}

__global__ void k_count(const int* __restrict__ dst, int* degc, int e) {
    int i = blockIdx.x * blockDim.x + threadIdx.x;
    if (i < e) atomicAdd(&degc[dst[i]], 1);
}

__global__ void k_blocksum(const int* __restrict__ degc, int* __restrict__ bsum, int n) {
    int i = blockIdx.x * 256 + threadIdx.x;
    int v = (i < n) ? degc[i] : 0;
    #pragma unroll
    for (int off = 32; off > 0; off >>= 1) v += __shfl_down(v, off, 64);
    __shared__ int ws[4];
    if ((threadIdx.x & 63) == 0) ws[threadIdx.x >> 6] = v;
    __syncthreads();
    if (threadIdx.x == 0) bsum[blockIdx.x] = ws[0] + ws[1] + ws[2] + ws[3];
}

__global__ void k_scanbsum(int* bsum, int nb) {
    __shared__ int s[256];
    int t = threadIdx.x;
    int v = (t < nb) ? bsum[t] : 0;
    s[t] = v;
    __syncthreads();
    #pragma unroll
    for (int off = 1; off < 256; off <<= 1) {
        int u = (t >= off) ? s[t - off] : 0;
        __syncthreads();
        s[t] += u;
        __syncthreads();
    }
    if (t < nb) bsum[t] = (t == 0) ? 0 : s[t - 1];
}

__global__ void k_rowptr(const int* __restrict__ degc, const int* __restrict__ bsum,
                         int* __restrict__ row_ptr, int* __restrict__ cursor,
                         float* __restrict__ dinv, int n) {
    __shared__ int s[256];
    int i = blockIdx.x * 256 + threadIdx.x;
    int t = threadIdx.x;
    int d = (i < n) ? degc[i] : 0;
    s[t] = d;
    __syncthreads();
    #pragma unroll
    for (int off = 1; off < 256; off <<= 1) {
        int u = (t >= off) ? s[t - off] : 0;
        __syncthreads();
        s[t] += u;
        __syncthreads();
    }
    int ex = s[t] - d + bsum[blockIdx.x];
    if (i < n) {
        row_ptr[i] = ex;
        cursor[i]  = ex;
        dinv[i]    = rsqrtf(1.0f + (float)d);
        if (i == n - 1) row_ptr[n] = ex + d;
    }
}

// 4-byte CSR entry: src (16 bits, N<65536) | fp16 weight << 16
__global__ void k_fill(const int* __restrict__ src, const int* __restrict__ dst,
                       const float* __restrict__ dinv, int* cursor,
                       unsigned* __restrict__ csr_ew, int e) {
    int i = blockIdx.x * blockDim.x + threadIdx.x;
    if (i < e) {
        int s = src[i], d = dst[i];
        int p = atomicAdd(&cursor[d], 1);
        __half h = __float2half(dinv[s] * dinv[d]);
        csr_ew[p] = (unsigned)s | ((unsigned)__half_as_ushort(h) << 16);
    }
}

__global__ void k_packx(const float* __restrict__ x, unsigned* __restrict__ xh, int npairs) {
    int i = blockIdx.x * blockDim.x + threadIdx.x;
    if (i < npairs) {
        float2 v = ((const float2*)x)[i];
        xh[i] = pack_bf2(v.x, v.y);
    }
}

// ---------------- 8-deep predicated bf16 gather, 4B edges (shared macro) ----------------

#define AGG_BODY(T2, W4, g, j, acc)                                             \
    {                                                                           \
        int lo = row_ptr[g], hi = row_ptr[(g) + 1];                             \
        for (int k = lo; k < hi; k += 8) {                                      \
            unsigned e0 = csr_ew[min(k + 0, hi - 1)];                           \
            unsigned e1 = csr_ew[min(k + 1, hi - 1)];                           \
            unsigned e2 = csr_ew[min(k + 2, hi - 1)];                           \
            unsigned e3 = csr_ew[min(k + 3, hi - 1)];                           \
            unsigned e4 = csr_ew[min(k + 4, hi - 1)];                           \
            unsigned e5 = csr_ew[min(k + 5, hi - 1)];                           \
            unsigned e6 = csr_ew[min(k + 6, hi - 1)];                           \
            unsigned e7 = csr_ew[min(k + 7, hi - 1)];                           \
            float w0 = __half2float(__ushort_as_half((unsigned short)(e0 >> 16)));                     \
            float w1 = (k + 1 < hi) ? __half2float(__ushort_as_half((unsigned short)(e1 >> 16))) : 0.0f;\
            float w2 = (k + 2 < hi) ? __half2float(__ushort_as_half((unsigned short)(e2 >> 16))) : 0.0f;\
            float w3 = (k + 3 < hi) ? __half2float(__ushort_as_half((unsigned short)(e3 >> 16))) : 0.0f;\
            float w4 = (k + 4 < hi) ? __half2float(__ushort_as_half((unsigned short)(e4 >> 16))) : 0.0f;\
            float w5 = (k + 5 < hi) ? __half2float(__ushort_as_half((unsigned short)(e5 >> 16))) : 0.0f;\
            float w6 = (k + 6 < hi) ? __half2float(__ushort_as_half((unsigned short)(e6 >> 16))) : 0.0f;\
            float w7 = (k + 7 < hi) ? __half2float(__ushort_as_half((unsigned short)(e7 >> 16))) : 0.0f;\
            uint2 t0 = T2[(size_t)(e0 & 0xffffu) * (W4) + (j)];                 \
            uint2 t1 = T2[(size_t)(e1 & 0xffffu) * (W4) + (j)];                 \
            uint2 t2 = T2[(size_t)(e2 & 0xffffu) * (W4) + (j)];                 \
            uint2 t3 = T2[(size_t)(e3 & 0xffffu) * (W4) + (j)];                 \
            uint2 t4 = T2[(size_t)(e4 & 0xffffu) * (W4) + (j)];                 \
            uint2 t5 = T2[(size_t)(e5 & 0xffffu) * (W4) + (j)];                 \
            uint2 t6 = T2[(size_t)(e6 & 0xffffu) * (W4) + (j)];                 \
            uint2 t7 = T2[(size_t)(e7 & 0xffffu) * (W4) + (j)];                 \
            AGG_ACC(t0, w0) AGG_ACC(t1, w1) AGG_ACC(t2, w2) AGG_ACC(t3, w3)     \
            AGG_ACC(t4, w4) AGG_ACC(t5, w5) AGG_ACC(t6, w6) AGG_ACC(t7, w7)     \
        }                                                                       \
    }

#define AGG_ACC(tv, wv)                                   \
        acc.x += wv * __uint_as_float(tv.x << 16);        \
        acc.y += wv * __uint_as_float(tv.x & 0xffff0000u);\
        acc.z += wv * __uint_as_float(tv.y << 16);        \
        acc.w += wv * __uint_as_float(tv.y & 0xffff0000u);

// ---------------- agg1 (x bf16, W4=11) -> bf16 out (linear, coalesced) ----------------

__global__ void k_agg1(const unsigned* __restrict__ T, const float* __restrict__ dinv,
                       const int* __restrict__ row_ptr, const unsigned* __restrict__ csr_ew,
                       unsigned short* __restrict__ O, int n) {
    int idx = blockIdx.x * 256 + threadIdx.x;
    if (idx >= n * 11) return;
    int g = idx / 11;
    int j = idx - g * 11;

    const uint2* T2 = (const uint2*)T;
    float di = dinv[g];
    float sw = di * di;
    uint2 sv = T2[(size_t)g * 11 + j];
    float4 acc;
    acc.x = sw * __uint_as_float(sv.x << 16);
    acc.y = sw * __uint_as_float(sv.x & 0xffff0000u);
    acc.z = sw * __uint_as_float(sv.y << 16);
    acc.w = sw * __uint_as_float(sv.y & 0xffff0000u);
    AGG_BODY(T2, 11, g, j, acc)
    uint2 o;
    o.x = pack_bf2(acc.x, acc.y);
    o.y = pack_bf2(acc.z, acc.w);
    ((uint2*)O)[(size_t)g * 11 + j] = o;
}

// ---------------- gemm1: aggX(bf16,44) @ W1 -> relu -> bf16 PANELS ----------------
// Panel p = blockIdx.y holds columns [16p,16p+16), laid out [p][node][16].

__global__ void k_gemm1p(const unsigned short* __restrict__ Xh, const float* __restrict__ W,
                         const float* __restrict__ b, unsigned short* __restrict__ P, int n) {
    const int ct0 = blockIdx.y * 16;
    int node = blockIdx.x * blockDim.x + threadIdx.x;
    if (node >= n) return;

    float acc[16];
    #pragma unroll
    for (int c = 0; c < 16; ++c) acc[c] = b[ct0 + c];

    const uint2* xr = (const uint2*)(Xh + (size_t)node * 44);
    const float* Wb = W + ct0;
    #pragma unroll
    for (int k0 = 0; k0 < 11; ++k0) {
        uint2 xv = xr[k0];
        float x0 = __uint_as_float(xv.x << 16);
        float x1 = __uint_as_float(xv.x & 0xffff0000u);
        float x2 = __uint_as_float(xv.y << 16);
        float x3 = __uint_as_float(xv.y & 0xffff0000u);
        #pragma unroll
        for (int c = 0; c < 16; ++c) acc[c] += x0 * Wb[(k0 * 4 + 0) * 128 + c];
        #pragma unroll
        for (int c = 0; c < 16; ++c) acc[c] += x1 * Wb[(k0 * 4 + 1) * 128 + c];
        #pragma unroll
        for (int c = 0; c < 16; ++c) acc[c] += x2 * Wb[(k0 * 4 + 2) * 128 + c];
        #pragma unroll
        for (int c = 0; c < 16; ++c) acc[c] += x3 * Wb[(k0 * 4 + 3) * 128 + c];
    }

    unsigned short* pr = P + ((size_t)blockIdx.y * n + node) * 16;
    #pragma unroll
    for (int c4 = 0; c4 < 4; ++c4) {
        float a0 = fmaxf(acc[c4 * 4 + 0], 0.0f);
        float a1 = fmaxf(acc[c4 * 4 + 1], 0.0f);
        float a2 = fmaxf(acc[c4 * 4 + 2], 0.0f);
        float a3 = fmaxf(acc[c4 * 4 + 3], 0.0f);
        uint2 p;
        p.x = pack_bf2(a0, a1);
        p.y = pack_bf2(a2, a3);
        *(uint2*)(pr + c4 * 4) = p;
    }
}

// ---------------- gemm2: buf1 panels (bf16,128) @ W2 -> t2 bf16 row-major ----------------
// One thread = FULL 64-col row: 128B contiguous write (no partial-line RMW),
// W addresses wave-uniform (scalar loads). K-loop NOT fully unrolled (code size).

__global__ void k_gemm2f(const unsigned short* __restrict__ P, const float* __restrict__ W,
                         unsigned short* __restrict__ H, int n) {
    int node = blockIdx.x * 256 + threadIdx.x;
    if (node >= n) return;

    float acc[64];
    #pragma unroll
    for (int c = 0; c < 64; ++c) acc[c] = 0.0f;

    #pragma unroll 2
    for (int k0 = 0; k0 < 32; ++k0) {
        int panel = k0 >> 2;
        int po    = (k0 & 3) * 4;
        uint2 xv = *(const uint2*)(P + ((size_t)panel * n + node) * 16 + po);
        float x0 = __uint_as_float(xv.x << 16);
        float x1 = __uint_as_float(xv.x & 0xffff0000u);
        float x2 = __uint_as_float(xv.y << 16);
        float x3 = __uint_as_float(xv.y & 0xffff0000u);
        const float* Wr = W + (size_t)(k0 * 4) * 64;
        #pragma unroll
        for (int c = 0; c < 64; ++c) acc[c] += x0 * Wr[c];
        #pragma unroll
        for (int c = 0; c < 64; ++c) acc[c] += x1 * Wr[64 + c];
        #pragma unroll
        for (int c = 0; c < 64; ++c) acc[c] += x2 * Wr[128 + c];
        #pragma unroll
        for (int c = 0; c < 64; ++c) acc[c] += x3 * Wr[192 + c];
    }

    unsigned short* hr = H + (size_t)node * 64;
    #pragma unroll
    for (int c8 = 0; c8 < 8; ++c8) {
        uint4 p;
        p.x = pack_bf2(acc[c8 * 8 + 0], acc[c8 * 8 + 1]);
        p.y = pack_bf2(acc[c8 * 8 + 2], acc[c8 * 8 + 3]);
        p.z = pack_bf2(acc[c8 * 8 + 4], acc[c8 * 8 + 5]);
        p.w = pack_bf2(acc[c8 * 8 + 6], acc[c8 * 8 + 7]);
        *(uint4*)(hr + c8 * 8) = p;
    }
}

// ---------------- fused agg2+gemm3: agg(t2,+b2,relu) -> .@W3 -> bf16 ----------------
// 64 threads = 1 wave = 4 nodes x 16 lanes.

__global__ void __launch_bounds__(64) k_fused23(
        const unsigned* __restrict__ T, const float* __restrict__ dinv,
        const int* __restrict__ row_ptr, const unsigned* __restrict__ csr_ew,
        const float* __restrict__ b2, const float* __restrict__ W3,
        unsigned short* __restrict__ outH, int n) {
    __shared__ float Xs[4 * 68];     // 64 + 4 pad
    const int m = threadIdx.x / 16;
    const int j = threadIdx.x % 16;
    const int g = blockIdx.x * 4 + m;
    const int gm = min(g, n - 1);

    const uint2* T2 = (const uint2*)T;
    {
        float di = dinv[gm];
        float sw = di * di;
        uint2 sv = T2[(size_t)gm * 16 + j];
        float4 acc;
        acc.x = sw * __uint_as_float(sv.x << 16);
        acc.y = sw * __uint_as_float(sv.x & 0xffff0000u);
        acc.z = sw * __uint_as_float(sv.y << 16);
        acc.w = sw * __uint_as_float(sv.y & 0xffff0000u);
        AGG_BODY(T2, 16, gm, j, acc)
        float4 bv = ((const float4*)b2)[j];
        acc.x = fmaxf(acc.x + bv.x, 0.0f);
        acc.y = fmaxf(acc.y + bv.y, 0.0f);
        acc.z = fmaxf(acc.z + bv.z, 0.0f);
        acc.w = fmaxf(acc.w + bv.w, 0.0f);
        *(float4*)&Xs[m * 68 + 4 * j] = acc;
    }
    __syncthreads();

    // gemm3: cols c = j*2
    {
        const int c = j * 2;
        float ax = 0.0f, ay = 0.0f;
        #pragma unroll 4
        for (int k4 = 0; k4 < 16; ++k4) {
            float4 hv = *(const float4*)&Xs[m * 68 + 4 * k4];
#define F3_STEP(hs, kk) { \
            float2 wv = *(const float2*)&W3[(kk) * 32 + c]; \
            ax += (hs) * wv.x; ay += (hs) * wv.y; }
            F3_STEP(hv.x, 4 * k4 + 0)
            F3_STEP(hv.y, 4 * k4 + 1)
            F3_STEP(hv.z, 4 * k4 + 2)
            F3_STEP(hv.w, 4 * k4 + 3)
#undef F3_STEP
        }
        if (g < n) *(unsigned*)(outH + (size_t)g * 32 + c) = pack_bf2(ax, ay);
    }
}

// ---------------- fused agg3+MLP head ----------------
// 64 threads = 1 wave = 8 nodes x 8 lanes.

__global__ void __launch_bounds__(64) k_fused3m(
        const unsigned* __restrict__ T, const float* __restrict__ dinv,
        const int* __restrict__ row_ptr, const unsigned* __restrict__ csr_ew,
        const float* __restrict__ b3,
        const float* __restrict__ Wf1, const float* __restrict__ bf1,
        const float* __restrict__ Wf2, const float* __restrict__ bf2,
        float* __restrict__ out, int n) {
    __shared__ float Xs[8 * 36];     // 32 + 4 pad
    const int m = threadIdx.x / 8;
    const int j = threadIdx.x % 8;
    const int g = blockIdx.x * 8 + m;
    const int gm = min(g, n - 1);

    const uint2* T2 = (const uint2*)T;
    {
        float di = dinv[gm];
        float sw = di * di;
        uint2 sv = T2[(size_t)gm * 8 + j];
        float4 acc;
        acc.x = sw * __uint_as_float(sv.x << 16);
        acc.y = sw * __uint_as_float(sv.x & 0xffff0000u);
        acc.z = sw * __uint_as_float(sv.y << 16);
        acc.w = sw * __uint_as_float(sv.y & 0xffff0000u);
        AGG_BODY(T2, 8, gm, j, acc)
        float4 bv = ((const float4*)b3)[j];
        acc.x = fmaxf(acc.x + bv.x, 0.0f);
        acc.y = fmaxf(acc.y + bv.y, 0.0f);
        acc.z = fmaxf(acc.z + bv.z, 0.0f);
        acc.w = fmaxf(acc.w + bv.w, 0.0f);
        *(float4*)&Xs[m * 36 + 4 * j] = acc;
    }
    __syncthreads();

    // MLP: lane j computes hidden cols 2j, 2j+1; shuffle-reduce 8 lanes
    {
        const int c = j * 2;
        float h0 = bf1[c], h1 = bf1[c + 1];
        #pragma unroll
        for (int k = 0; k < 32; ++k) {
            float xs = Xs[m * 36 + k];
            float2 wv = *(const float2*)&Wf1[k * 16 + c];
            h0 += xs * wv.x;
            h1 += xs * wv.y;
        }
        float2 w2 = *(const float2*)&Wf2[c];
        float partial = fmaxf(h0, 0.0f) * w2.x + fmaxf(h1, 0.0f) * w2.y;
        partial += __shfl_down(partial, 4);
        partial += __shfl_down(partial, 2);
        partial += __shfl_down(partial, 1);
        if (j == 0 && g < n) out[g] = 1.0f / (1.0f + expf(-(partial + bf2[0])));
    }
}

// ---------------- launch ----------------

extern "C" void kernel_launch(void* const* d_in, const int* in_sizes, int n_in,
                              void* d_out, int out_size, void* d_ws, size_t ws_size,
                              hipStream_t stream) {
    const float* x   = (const float*)d_in[0];
    const int*   ei  = (const int*)d_in[1];
    const float* W1  = (const float*)d_in[2];
    const float* b1  = (const float*)d_in[3];
    const float* W2  = (const float*)d_in[4];
    const float* b2  = (const float*)d_in[5];
    const float* W3  = (const float*)d_in[6];
    const float* b3  = (const float*)d_in[7];
    const float* Wf1 = (const float*)d_in[8];
    const float* bf1 = (const float*)d_in[9];
    const float* Wf2 = (const float*)d_in[10];
    const float* bf2 = (const float*)d_in[11];
    float* out = (float*)d_out;

    const int N = N_NODES, E = N_EDGES;
    const int* src = ei;
    const int* dst = ei + E;

    const int B   = 256;
    const int NB  = (N + B - 1) / B;        // 196
    const int NBX = 200;                    // multiple of 8 (XCD count)

    char* w = (char*)d_ws;
    float*    dinv    = (float*)w;     w += (size_t)N * 4;
    int*      degc    = (int*)w;       w += (size_t)N * 4;
    int*      row_ptr = (int*)w;       w += (size_t)(N + 4) * 4;
    int*      cursor  = (int*)w;       w += (size_t)N * 4;
    int*      bsum    = (int*)w;       w += (size_t)256 * 4;
    unsigned* csr_ew  = (unsigned*)w;  w += (size_t)E * 4;
    unsigned* xh      = (unsigned*)w;  w += (size_t)N * 44 * 2;   // x bf16
    unsigned short* aggXh = (unsigned short*)w;  w += (size_t)N * 44 * 2;   // agg1 out bf16
    unsigned short* buf1p = (unsigned short*)w;  w += (size_t)N * 128 * 2;  // h1 bf16 panels
    unsigned short* bufAh = (unsigned short*)w;  w += (size_t)N * 64 * 2;   // t2 bf16
    unsigned short* bufBh = (unsigned short*)w;  w += (size_t)N * 32 * 2;   // t3 bf16

    // ---- CSR build + x packing ----
    k_zero     <<<NB, B, 0, stream>>>(degc, N);
    k_packx    <<<(N * 22 + B - 1) / B, B, 0, stream>>>(x, xh, N * 22);
    k_count    <<<(E + B - 1) / B, B, 0, stream>>>(dst, degc, E);
    k_blocksum <<<NB, B, 0, stream>>>(degc, bsum, N);
    k_scanbsum <<<1, B, 0, stream>>>(bsum, NB);
    k_rowptr   <<<NB, B, 0, stream>>>(degc, bsum, row_ptr, cursor, dinv, N);
    k_fill     <<<(E + B - 1) / B, B, 0, stream>>>(src, dst, dinv, cursor, csr_ew, E);

    // ---- layer 1: agg x(bf16) -> gemm1 (panels out) -> gemm2 (full-row, bf16 out) ----
    k_agg1  <<<(N * 11 + B - 1) / B, B, 0, stream>>>(xh, dinv, row_ptr, csr_ew, aggXh, N);
    k_gemm1p<<<dim3(NBX, 8), B, 0, stream>>>(aggXh, W1, b1, buf1p, N);
    k_gemm2f<<<NBX, B, 0, stream>>>(buf1p, W2, bufAh, N);

    // ---- layer 2+3: fused agg2+gemm3 -> t3 (bf16) ----
    k_fused23<<<(N + 3) / 4, 64, 0, stream>>>((const unsigned*)bufAh, dinv, row_ptr,
                                              csr_ew, b2, W3, bufBh, N);

    // ---- layer 3 agg + MLP head ----
    k_fused3m<<<(N + 7) / 8, 64, 0, stream>>>((const unsigned*)bufBh, dinv, row_ptr,
                                              csr_ew, b3, Wf1, bf1, Wf2, bf2, out, N);
}

// Round 24
// 262.143 us; speedup vs baseline: 1.1399x; 1.1399x over previous
//
#include <hip/hip_runtime.h>
#include <hip/hip_bf16.h>
#include <hip/hip_fp16.h>
#include <math.h>

#define N_NODES 50000
#define N_EDGES 600000
#define D_IN    44

// ---------------- bf16 helpers (bit ops, RNE pack) ----------------

__device__ __forceinline__ unsigned pack_bf2(float a, float b) {
    unsigned ua = __float_as_uint(a);
    ua = (ua + 0x7fffu + ((ua >> 16) & 1u)) >> 16;
    unsigned ub = __float_as_uint(b);
    ub = (ub + 0x7fffu + ((ub >> 16) & 1u)) & 0xffff0000u;
    return ua | ub;
}

// ---------------- CSR build ----------------

__global__ void k_zero(int* p, int n) {
    int i = blockIdx.x * blockDim.x + threadIdx.x;
    if (i < n) p[i] = 0;
}

__global__ void k_count(const int* __restrict__ dst, int* degc, int e) {
    int i = blockIdx.x * blockDim.x + threadIdx.x;
    if (i < e) atomicAdd(&degc[dst[i]], 1);
}

__global__ void k_blocksum(const int* __restrict__ degc, int* __restrict__ bsum, int n) {
    int i = blockIdx.x * 256 + threadIdx.x;
    int v = (i < n) ? degc[i] : 0;
    #pragma unroll
    for (int off = 32; off > 0; off >>= 1) v += __shfl_down(v, off, 64);
    __shared__ int ws[4];
    if ((threadIdx.x & 63) == 0) ws[threadIdx.x >> 6] = v;
    __syncthreads();
    if (threadIdx.x == 0) bsum[blockIdx.x] = ws[0] + ws[1] + ws[2] + ws[3];
}

__global__ void k_scanbsum(int* bsum, int nb) {
    __shared__ int s[256];
    int t = threadIdx.x;
    int v = (t < nb) ? bsum[t] : 0;
    s[t] = v;
    __syncthreads();
    #pragma unroll
    for (int off = 1; off < 256; off <<= 1) {
        int u = (t >= off) ? s[t - off] : 0;
        __syncthreads();
        s[t] += u;
        __syncthreads();
    }
    if (t < nb) bsum[t] = (t == 0) ? 0 : s[t - 1];
}

__global__ void k_rowptr(const int* __restrict__ degc, const int* __restrict__ bsum,
                         int* __restrict__ row_ptr, int* __restrict__ cursor,
                         float* __restrict__ dinv, int n) {
    __shared__ int s[256];
    int i = blockIdx.x * 256 + threadIdx.x;
    int t = threadIdx.x;
    int d = (i < n) ? degc[i] : 0;
    s[t] = d;
    __syncthreads();
    #pragma unroll
    for (int off = 1; off < 256; off <<= 1) {
        int u = (t >= off) ? s[t - off] : 0;
        __syncthreads();
        s[t] += u;
        __syncthreads();
    }
    int ex = s[t] - d + bsum[blockIdx.x];
    if (i < n) {
        row_ptr[i] = ex;
        cursor[i]  = ex;
        dinv[i]    = rsqrtf(1.0f + (float)d);
        if (i == n - 1) row_ptr[n] = ex + d;
    }
}

// 4-byte CSR entry: src (16 bits, N<65536) | fp16 weight << 16
__global__ void k_fill(const int* __restrict__ src, const int* __restrict__ dst,
                       const float* __restrict__ dinv, int* cursor,
                       unsigned* __restrict__ csr_ew, int e) {
    int i = blockIdx.x * blockDim.x + threadIdx.x;
    if (i < e) {
        int s = src[i], d = dst[i];
        int p = atomicAdd(&cursor[d], 1);
        __half h = __float2half(dinv[s] * dinv[d]);
        csr_ew[p] = (unsigned)s | ((unsigned)__half_as_ushort(h) << 16);
    }
}

__global__ void k_packx(const float* __restrict__ x, unsigned* __restrict__ xh, int npairs) {
    int i = blockIdx.x * blockDim.x + threadIdx.x;
    if (i < npairs) {
        float2 v = ((const float2*)x)[i];
        xh[i] = pack_bf2(v.x, v.y);
    }
}

// ---------------- 8-deep predicated bf16 gather, 4B edges (shared macro) ----------------

#define AGG_BODY(T2, W4, g, j, acc)                                             \
    {                                                                           \
        int lo = row_ptr[g], hi = row_ptr[(g) + 1];                             \
        for (int k = lo; k < hi; k += 8) {                                      \
            unsigned e0 = csr_ew[min(k + 0, hi - 1)];                           \
            unsigned e1 = csr_ew[min(k + 1, hi - 1)];                           \
            unsigned e2 = csr_ew[min(k + 2, hi - 1)];                           \
            unsigned e3 = csr_ew[min(k + 3, hi - 1)];                           \
            unsigned e4 = csr_ew[min(k + 4, hi - 1)];                           \
            unsigned e5 = csr_ew[min(k + 5, hi - 1)];                           \
            unsigned e6 = csr_ew[min(k + 6, hi - 1)];                           \
            unsigned e7 = csr_ew[min(k + 7, hi - 1)];                           \
            float w0 = __half2float(__ushort_as_half((unsigned short)(e0 >> 16)));                     \
            float w1 = (k + 1 < hi) ? __half2float(__ushort_as_half((unsigned short)(e1 >> 16))) : 0.0f;\
            float w2 = (k + 2 < hi) ? __half2float(__ushort_as_half((unsigned short)(e2 >> 16))) : 0.0f;\
            float w3 = (k + 3 < hi) ? __half2float(__ushort_as_half((unsigned short)(e3 >> 16))) : 0.0f;\
            float w4 = (k + 4 < hi) ? __half2float(__ushort_as_half((unsigned short)(e4 >> 16))) : 0.0f;\
            float w5 = (k + 5 < hi) ? __half2float(__ushort_as_half((unsigned short)(e5 >> 16))) : 0.0f;\
            float w6 = (k + 6 < hi) ? __half2float(__ushort_as_half((unsigned short)(e6 >> 16))) : 0.0f;\
            float w7 = (k + 7 < hi) ? __half2float(__ushort_as_half((unsigned short)(e7 >> 16))) : 0.0f;\
            uint2 t0 = T2[(size_t)(e0 & 0xffffu) * (W4) + (j)];                 \
            uint2 t1 = T2[(size_t)(e1 & 0xffffu) * (W4) + (j)];                 \
            uint2 t2 = T2[(size_t)(e2 & 0xffffu) * (W4) + (j)];                 \
            uint2 t3 = T2[(size_t)(e3 & 0xffffu) * (W4) + (j)];                 \
            uint2 t4 = T2[(size_t)(e4 & 0xffffu) * (W4) + (j)];                 \
            uint2 t5 = T2[(size_t)(e5 & 0xffffu) * (W4) + (j)];                 \
            uint2 t6 = T2[(size_t)(e6 & 0xffffu) * (W4) + (j)];                 \
            uint2 t7 = T2[(size_t)(e7 & 0xffffu) * (W4) + (j)];                 \
            AGG_ACC(t0, w0) AGG_ACC(t1, w1) AGG_ACC(t2, w2) AGG_ACC(t3, w3)     \
            AGG_ACC(t4, w4) AGG_ACC(t5, w5) AGG_ACC(t6, w6) AGG_ACC(t7, w7)     \
        }                                                                       \
    }

#define AGG_ACC(tv, wv)                                   \
        acc.x += wv * __uint_as_float(tv.x << 16);        \
        acc.y += wv * __uint_as_float(tv.x & 0xffff0000u);\
        acc.z += wv * __uint_as_float(tv.y << 16);        \
        acc.w += wv * __uint_as_float(tv.y & 0xffff0000u);

// ---------------- agg1 (x bf16, W4=11) -> bf16 out (linear, coalesced) ----------------

__global__ void k_agg1(const unsigned* __restrict__ T, const float* __restrict__ dinv,
                       const int* __restrict__ row_ptr, const unsigned* __restrict__ csr_ew,
                       unsigned short* __restrict__ O, int n) {
    int idx = blockIdx.x * 256 + threadIdx.x;
    if (idx >= n * 11) return;
    int g = idx / 11;
    int j = idx - g * 11;

    const uint2* T2 = (const uint2*)T;
    float di = dinv[g];
    float sw = di * di;
    uint2 sv = T2[(size_t)g * 11 + j];
    float4 acc;
    acc.x = sw * __uint_as_float(sv.x << 16);
    acc.y = sw * __uint_as_float(sv.x & 0xffff0000u);
    acc.z = sw * __uint_as_float(sv.y << 16);
    acc.w = sw * __uint_as_float(sv.y & 0xffff0000u);
    AGG_BODY(T2, 11, g, j, acc)
    uint2 o;
    o.x = pack_bf2(acc.x, acc.y);
    o.y = pack_bf2(acc.z, acc.w);
    ((uint2*)O)[(size_t)g * 11 + j] = o;
}

// ---------------- register-blocked GEMM, wave-uniform (scalar) W loads ----------------
// IN_BF16: X packed bf16; OUT_BF16: output packed bf16. CT=16.

template<int DI, int DO, int CT, bool BIAS_RELU, bool IN_BF16, bool OUT_BF16>
__global__ void k_gemm(const void* __restrict__ Xv, const float* __restrict__ W,
                       const float* __restrict__ b, void* __restrict__ H, int n) {
    const int ct0 = blockIdx.y * CT;
    int node = blockIdx.x * blockDim.x + threadIdx.x;
    if (node >= n) return;

    float acc[CT];
    #pragma unroll
    for (int c = 0; c < CT; ++c) acc[c] = BIAS_RELU ? b[ct0 + c] : 0.0f;

    const float* Wb = W + ct0;
    #pragma unroll
    for (int k0 = 0; k0 < DI / 4; ++k0) {
        float x0, x1, x2, x3;
        if (IN_BF16) {
            uint2 xv = ((const uint2*)((const unsigned short*)Xv + (size_t)node * DI))[k0];
            x0 = __uint_as_float(xv.x << 16);
            x1 = __uint_as_float(xv.x & 0xffff0000u);
            x2 = __uint_as_float(xv.y << 16);
            x3 = __uint_as_float(xv.y & 0xffff0000u);
        } else {
            float4 xv = ((const float4*)((const float*)Xv + (size_t)node * DI))[k0];
            x0 = xv.x; x1 = xv.y; x2 = xv.z; x3 = xv.w;
        }
        #pragma unroll
        for (int c = 0; c < CT; ++c) acc[c] += x0 * Wb[(k0 * 4 + 0) * DO + c];
        #pragma unroll
        for (int c = 0; c < CT; ++c) acc[c] += x1 * Wb[(k0 * 4 + 1) * DO + c];
        #pragma unroll
        for (int c = 0; c < CT; ++c) acc[c] += x2 * Wb[(k0 * 4 + 2) * DO + c];
        #pragma unroll
        for (int c = 0; c < CT; ++c) acc[c] += x3 * Wb[(k0 * 4 + 3) * DO + c];
    }

    #pragma unroll
    for (int c4 = 0; c4 < CT / 4; ++c4) {
        float4 v;
        v.x = acc[c4 * 4 + 0]; v.y = acc[c4 * 4 + 1];
        v.z = acc[c4 * 4 + 2]; v.w = acc[c4 * 4 + 3];
        if (BIAS_RELU) {
            v.x = fmaxf(v.x, 0.0f); v.y = fmaxf(v.y, 0.0f);
            v.z = fmaxf(v.z, 0.0f); v.w = fmaxf(v.w, 0.0f);
        }
        if (OUT_BF16) {
            uint2 p;
            p.x = pack_bf2(v.x, v.y);
            p.y = pack_bf2(v.z, v.w);
            ((uint2*)((unsigned short*)H + (size_t)node * DO + ct0))[c4] = p;
        } else {
            ((float4*)((float*)H + (size_t)node * DO + ct0))[c4] = v;
        }
    }
}

// ---------------- fused agg2+gemm3: agg(t2,+b2,relu) -> .@W3 -> bf16 ----------------
// 64 threads = 1 wave = 4 nodes x 16 lanes.

__global__ void __launch_bounds__(64) k_fused23(
        const unsigned* __restrict__ T, const float* __restrict__ dinv,
        const int* __restrict__ row_ptr, const unsigned* __restrict__ csr_ew,
        const float* __restrict__ b2, const float* __restrict__ W3,
        unsigned short* __restrict__ outH, int n) {
    __shared__ float Xs[4 * 68];     // 64 + 4 pad
    const int m = threadIdx.x / 16;
    const int j = threadIdx.x % 16;
    const int g = blockIdx.x * 4 + m;
    const int gm = min(g, n - 1);

    const uint2* T2 = (const uint2*)T;
    {
        float di = dinv[gm];
        float sw = di * di;
        uint2 sv = T2[(size_t)gm * 16 + j];
        float4 acc;
        acc.x = sw * __uint_as_float(sv.x << 16);
        acc.y = sw * __uint_as_float(sv.x & 0xffff0000u);
        acc.z = sw * __uint_as_float(sv.y << 16);
        acc.w = sw * __uint_as_float(sv.y & 0xffff0000u);
        AGG_BODY(T2, 16, gm, j, acc)
        float4 bv = ((const float4*)b2)[j];
        acc.x = fmaxf(acc.x + bv.x, 0.0f);
        acc.y = fmaxf(acc.y + bv.y, 0.0f);
        acc.z = fmaxf(acc.z + bv.z, 0.0f);
        acc.w = fmaxf(acc.w + bv.w, 0.0f);
        *(float4*)&Xs[m * 68 + 4 * j] = acc;
    }
    __syncthreads();

    // gemm3: cols c = j*2
    {
        const int c = j * 2;
        float ax = 0.0f, ay = 0.0f;
        #pragma unroll 4
        for (int k4 = 0; k4 < 16; ++k4) {
            float4 hv = *(const float4*)&Xs[m * 68 + 4 * k4];
#define F3_STEP(hs, kk) { \
            float2 wv = *(const float2*)&W3[(kk) * 32 + c]; \
            ax += (hs) * wv.x; ay += (hs) * wv.y; }
            F3_STEP(hv.x, 4 * k4 + 0)
            F3_STEP(hv.y, 4 * k4 + 1)
            F3_STEP(hv.z, 4 * k4 + 2)
            F3_STEP(hv.w, 4 * k4 + 3)
#undef F3_STEP
        }
        if (g < n) *(unsigned*)(outH + (size_t)g * 32 + c) = pack_bf2(ax, ay);
    }
}

// ---------------- fused agg3+MLP head ----------------
// 64 threads = 1 wave = 8 nodes x 8 lanes.

__global__ void __launch_bounds__(64) k_fused3m(
        const unsigned* __restrict__ T, const float* __restrict__ dinv,
        const int* __restrict__ row_ptr, const unsigned* __restrict__ csr_ew,
        const float* __restrict__ b3,
        const float* __restrict__ Wf1, const float* __restrict__ bf1,
        const float* __restrict__ Wf2, const float* __restrict__ bf2,
        float* __restrict__ out, int n) {
    __shared__ float Xs[8 * 36];     // 32 + 4 pad
    const int m = threadIdx.x / 8;
    const int j = threadIdx.x % 8;
    const int g = blockIdx.x * 8 + m;
    const int gm = min(g, n - 1);

    const uint2* T2 = (const uint2*)T;
    {
        float di = dinv[gm];
        float sw = di * di;
        uint2 sv = T2[(size_t)gm * 8 + j];
        float4 acc;
        acc.x = sw * __uint_as_float(sv.x << 16);
        acc.y = sw * __uint_as_float(sv.x & 0xffff0000u);
        acc.z = sw * __uint_as_float(sv.y << 16);
        acc.w = sw * __uint_as_float(sv.y & 0xffff0000u);
        AGG_BODY(T2, 8, gm, j, acc)
        float4 bv = ((const float4*)b3)[j];
        acc.x = fmaxf(acc.x + bv.x, 0.0f);
        acc.y = fmaxf(acc.y + bv.y, 0.0f);
        acc.z = fmaxf(acc.z + bv.z, 0.0f);
        acc.w = fmaxf(acc.w + bv.w, 0.0f);
        *(float4*)&Xs[m * 36 + 4 * j] = acc;
    }
    __syncthreads();

    // MLP: lane j computes hidden cols 2j, 2j+1; shuffle-reduce 8 lanes
    {
        const int c = j * 2;
        float h0 = bf1[c], h1 = bf1[c + 1];
        #pragma unroll
        for (int k = 0; k < 32; ++k) {
            float xs = Xs[m * 36 + k];
            float2 wv = *(const float2*)&Wf1[k * 16 + c];
            h0 += xs * wv.x;
            h1 += xs * wv.y;
        }
        float2 w2 = *(const float2*)&Wf2[c];
        float partial = fmaxf(h0, 0.0f) * w2.x + fmaxf(h1, 0.0f) * w2.y;
        partial += __shfl_down(partial, 4);
        partial += __shfl_down(partial, 2);
        partial += __shfl_down(partial, 1);
        if (j == 0 && g < n) out[g] = 1.0f / (1.0f + expf(-(partial + bf2[0])));
    }
}

// ---------------- launch ----------------

extern "C" void kernel_launch(void* const* d_in, const int* in_sizes, int n_in,
                              void* d_out, int out_size, void* d_ws, size_t ws_size,
                              hipStream_t stream) {
    const float* x   = (const float*)d_in[0];
    const int*   ei  = (const int*)d_in[1];
    const float* W1  = (const float*)d_in[2];
    const float* b1  = (const float*)d_in[3];
    const float* W2  = (const float*)d_in[4];
    const float* b2  = (const float*)d_in[5];
    const float* W3  = (const float*)d_in[6];
    const float* b3  = (const float*)d_in[7];
    const float* Wf1 = (const float*)d_in[8];
    const float* bf1 = (const float*)d_in[9];
    const float* Wf2 = (const float*)d_in[10];
    const float* bf2 = (const float*)d_in[11];
    float* out = (float*)d_out;

    const int N = N_NODES, E = N_EDGES;
    const int* src = ei;
    const int* dst = ei + E;

    const int B   = 256;
    const int NB  = (N + B - 1) / B;        // 196
    const int NBX = 200;                    // multiple of 8 (XCD count)

    char* w = (char*)d_ws;
    float*    dinv    = (float*)w;     w += (size_t)N * 4;
    int*      degc    = (int*)w;       w += (size_t)N * 4;
    int*      row_ptr = (int*)w;       w += (size_t)(N + 4) * 4;
    int*      cursor  = (int*)w;       w += (size_t)N * 4;
    int*      bsum    = (int*)w;       w += (size_t)256 * 4;
    unsigned* csr_ew  = (unsigned*)w;  w += (size_t)E * 4;
    unsigned* xh      = (unsigned*)w;  w += (size_t)N * 44 * 2;   // x bf16
    unsigned short* aggXh = (unsigned short*)w;  w += (size_t)N * 44 * 2;   // agg1 out bf16
    float*    buf1    = (float*)w;     w += (size_t)N * 128 * 4;  // h1 fp32
    unsigned short* bufAh = (unsigned short*)w;  w += (size_t)N * 64 * 2;   // t2 bf16
    unsigned short* bufBh = (unsigned short*)w;  w += (size_t)N * 32 * 2;   // t3 bf16

    // ---- CSR build + x packing ----
    k_zero     <<<NB, B, 0, stream>>>(degc, N);
    k_packx    <<<(N * 22 + B - 1) / B, B, 0, stream>>>(x, xh, N * 22);
    k_count    <<<(E + B - 1) / B, B, 0, stream>>>(dst, degc, E);
    k_blocksum <<<NB, B, 0, stream>>>(degc, bsum, N);
    k_scanbsum <<<1, B, 0, stream>>>(bsum, NB);
    k_rowptr   <<<NB, B, 0, stream>>>(degc, bsum, row_ptr, cursor, dinv, N);
    k_fill     <<<(E + B - 1) / B, B, 0, stream>>>(src, dst, dinv, cursor, csr_ew, E);

    // ---- layer 1: agg x(bf16, bf16 out) -> gemm1 bf16-in fp32-out -> gemm2 fp32-in bf16-out ----
    k_agg1<<<(N * 11 + B - 1) / B, B, 0, stream>>>(xh, dinv, row_ptr, csr_ew, aggXh, N);
    k_gemm<44, 128, 16, true, true, false><<<dim3(NBX, 8), B, 0, stream>>>(aggXh, W1, b1, buf1, N);
    k_gemm<128, 64, 16, false, false, true><<<dim3(NBX, 4), B, 0, stream>>>(buf1, W2, nullptr, bufAh, N);

    // ---- layer 2+3: fused agg2+gemm3 -> t3 (bf16) ----
    k_fused23<<<(N + 3) / 4, 64, 0, stream>>>((const unsigned*)bufAh, dinv, row_ptr,
                                              csr_ew, b2, W3, bufBh, N);

    // ---- layer 3 agg + MLP head ----
    k_fused3m<<<(N + 7) / 8, 64, 0, stream>>>((const unsigned*)bufBh, dinv, row_ptr,
                                              csr_ew, b3, Wf1, bf1, Wf2, bf2, out, N);
}